// Round 1
// baseline (503.102 us; speedup 1.0000x reference)
//
#include <hip/hip_runtime.h>
#include <hip/hip_bf16.h>
#include <stdint.h>

#define N_ANCH   8400
#define NUM_CLS  600
#define H_IMG    640
#define W_IMG    640
#define PRE_NMS  1024
#define M_MAX    31
#define OUT_SZ   224
#define SCORE_THRESH 0.1f
#define IOU_THRESH   0.45f

// ---------------------------------------------------------------------------
// K1: decode boxes + per-anchor max/argmax over 600 classes.
// 512 threads = 64 anchors x 8 class-partitions (75 classes each).
// ---------------------------------------------------------------------------
__global__ __launch_bounds__(512) void k_prep(
    const float* __restrict__ raw,
    float* __restrict__ x1, float* __restrict__ y1,
    float* __restrict__ x2, float* __restrict__ y2,
    float* __restrict__ sc, int* __restrict__ cls) {
  __shared__ float s_m[8][64];
  __shared__ int   s_mi[8][64];
  const int lane = threadIdx.x & 63;
  const int part = threadIdx.x >> 6;       // 0..7
  const int a = blockIdx.x * 64 + lane;

  float m = -INFINITY; int mi = 0;
  if (a < N_ANCH) {
    const float* lp = raw + (size_t)(4 + part * 75) * N_ANCH + a;
    #pragma unroll 5
    for (int cc = 0; cc < 75; ++cc) {
      float v = lp[(size_t)cc * N_ANCH];
      if (v > m) { m = v; mi = part * 75 + cc; }
    }
  }
  s_m[part][lane] = m; s_mi[part][lane] = mi;
  __syncthreads();
  if (part == 0 && a < N_ANCH) {
    #pragma unroll
    for (int p = 1; p < 8; ++p) {
      float vm = s_m[p][lane];
      if (vm > m) { m = vm; mi = s_mi[p][lane]; }   // ascending parts -> ties keep first
    }
    sc[a] = m; cls[a] = mi;
    float cx = raw[a];
    float cy = raw[(size_t)1 * N_ANCH + a];
    float w  = raw[(size_t)2 * N_ANCH + a];
    float h  = raw[(size_t)3 * N_ANCH + a];
    x1[a] = cx - w * 0.5f; y1[a] = cy - h * 0.5f;
    x2[a] = cx + w * 0.5f; y2[a] = cy + h * 0.5f;
  }
}

// ---------------------------------------------------------------------------
// K2: exact top-1024 (score desc, index asc) via 64-bit-key radix select +
// bitonic sort. One block of 1024 threads.
// key = (score_bits << 32) | (0xFFFFFFFF - idx)   (all keys distinct)
// ---------------------------------------------------------------------------
__global__ __launch_bounds__(1024) void k_select(
    const float* __restrict__ sc, const int* __restrict__ cls,
    const float* __restrict__ x1, const float* __restrict__ y1,
    const float* __restrict__ x2, const float* __restrict__ y2,
    float* __restrict__ t_sc, float* __restrict__ tb, int* __restrict__ t_cl) {
  __shared__ float s_sc[N_ANCH];
  __shared__ unsigned long long s_keys[PRE_NMS];
  __shared__ int s_icnt[16];
  __shared__ int s_tot;
  __shared__ int s_cnt;
  const int tid = threadIdx.x;

  for (int a = tid; a < N_ANCH; a += 1024) s_sc[a] = sc[a];
  if (tid == 0) s_cnt = 0;
  __syncthreads();

  unsigned long long prefix = 0ULL;
  int need = PRE_NMS;
  for (int bit = 63; bit >= 0; --bit) {
    const unsigned long long test   = prefix | (1ULL << bit);
    const unsigned long long maskhi = ~((1ULL << bit) - 1ULL);
    int c = 0;
    for (int a = tid; a < N_ANCH; a += 1024) {
      unsigned long long key =
          (((unsigned long long)__float_as_uint(s_sc[a])) << 32) |
          (unsigned long long)(0xFFFFFFFFu - (unsigned)a);
      if ((key & maskhi) == test) ++c;
    }
    #pragma unroll
    for (int o = 32; o > 0; o >>= 1) c += __shfl_down(c, o, 64);
    if ((tid & 63) == 0) s_icnt[tid >> 6] = c;
    __syncthreads();
    if (tid == 0) {
      int tot = 0;
      #pragma unroll
      for (int wv = 0; wv < 16; ++wv) tot += s_icnt[wv];
      s_tot = tot;
    }
    __syncthreads();
    const int total = s_tot;
    if (total >= need) prefix = test; else need -= total;
  }

  // gather the exactly-1024 keys >= prefix (order fixed by the sort below)
  for (int a = tid; a < N_ANCH; a += 1024) {
    unsigned long long key =
        (((unsigned long long)__float_as_uint(s_sc[a])) << 32) |
        (unsigned long long)(0xFFFFFFFFu - (unsigned)a);
    if (key >= prefix) {
      int p = atomicAdd(&s_cnt, 1);
      if (p < PRE_NMS) s_keys[p] = key;
    }
  }
  __syncthreads();

  // bitonic sort, descending
  for (int k = 2; k <= PRE_NMS; k <<= 1) {
    for (int j = k >> 1; j > 0; j >>= 1) {
      __syncthreads();
      const int i = tid;
      const int ixj = i ^ j;
      if (ixj > i) {
        unsigned long long va = s_keys[i], vb = s_keys[ixj];
        bool desc = ((i & k) == 0);
        bool sw = desc ? (va < vb) : (va > vb);
        if (sw) { s_keys[i] = vb; s_keys[ixj] = va; }
      }
    }
  }
  __syncthreads();

  const unsigned long long key = s_keys[tid];
  const int idx = (int)(0xFFFFFFFFu - (unsigned)(key & 0xFFFFFFFFULL));
  t_sc[tid] = __uint_as_float((unsigned)(key >> 32));
  tb[tid]               = x1[idx];
  tb[PRE_NMS + tid]     = y1[idx];
  tb[2 * PRE_NMS + tid] = x2[idx];
  tb[3 * PRE_NMS + tid] = y2[idx];
  t_cl[tid] = cls[idx];
}

// ---------------------------------------------------------------------------
// K3: suppression-mask matrix. word(i,w) bit l set iff IoU(i, j)>thr && j>i,
// j = w*64 + ((l + 4w) & 63)  (rotation kills the 16-way LDS bank conflict).
// ---------------------------------------------------------------------------
__global__ __launch_bounds__(256) void k_iou_mask(
    const float* __restrict__ tb, unsigned long long* __restrict__ mask) {
  __shared__ float bx1[PRE_NMS], by1[PRE_NMS], bx2[PRE_NMS], by2[PRE_NMS], bar[PRE_NMS];
  const int tid = threadIdx.x;
  for (int a = tid; a < PRE_NMS; a += 256) {
    float X1 = tb[a], Y1 = tb[PRE_NMS + a], X2 = tb[2 * PRE_NMS + a], Y2 = tb[3 * PRE_NMS + a];
    bx1[a] = X1; by1[a] = Y1; bx2[a] = X2; by2[a] = Y2;
    bar[a] = (X2 - X1) * (Y2 - Y1);
  }
  __syncthreads();
  const int g = blockIdx.x * 256 + tid;      // 0..16383
  const int i = g >> 4;
  const int w = g & 15;
  const float ix1 = bx1[i], iy1 = by1[i], ix2 = bx2[i], iy2 = by2[i], ia = bar[i];
  unsigned long long m = 0ULL;
  const int j0 = w * 64;
  #pragma unroll 8
  for (int l = 0; l < 64; ++l) {
    const int jj = (l + 4 * w) & 63;
    const int j = j0 + jj;
    float ltx = fmaxf(ix1, bx1[j]);
    float lty = fmaxf(iy1, by1[j]);
    float rbx = fminf(ix2, bx2[j]);
    float rby = fminf(iy2, by2[j]);
    float ww = fmaxf(rbx - ltx, 0.0f);
    float hh = fmaxf(rby - lty, 0.0f);
    float inter = ww * hh;
    float uni = ia + bar[j] - inter;
    float iou = inter / fmaxf(uni, 1e-12f);
    if (iou > IOU_THRESH && j > i) m |= (1ULL << jj);
  }
  mask[(size_t)i * 16 + w] = m;
}

// ---------------------------------------------------------------------------
// K4: serial greedy-NMS reduce (single wave; lanes 0..15 hold the 1024-bit
// suppressed mask), then valid filter + stable first-31 selection + header
// outputs + 96 scaled crop boxes.
// ---------------------------------------------------------------------------
__global__ __launch_bounds__(64) void k_nms_final(
    const unsigned long long* __restrict__ mask,
    const float* __restrict__ t_sc, const float* __restrict__ tb,
    const int* __restrict__ t_cl, const int* __restrict__ allowed, int n_allowed,
    float* __restrict__ out, float* __restrict__ cropbox) {
  __shared__ unsigned long long s_supp[16];
  __shared__ int s_alw[64];
  __shared__ int s_selr[M_MAX];
  __shared__ int s_nsel;
  const int lane = threadIdx.x;

  unsigned long long supp = 0ULL;
  unsigned long long pre[8];
  #pragma unroll
  for (int d = 0; d < 8; ++d)
    pre[d] = (lane < 16) ? mask[(size_t)d * 16 + lane] : 0ULL;

  for (int i0 = 0; i0 < PRE_NMS; i0 += 8) {
    #pragma unroll
    for (int d = 0; d < 8; ++d) {
      const int i = i0 + d;
      unsigned long long row = pre[d];
      if (i + 8 < PRE_NMS && lane < 16) pre[d] = mask[(size_t)(i + 8) * 16 + lane];
      unsigned long long wsup = __shfl(supp, i >> 6, 64);
      bool kept = ((wsup >> (unsigned)(i & 63)) & 1ULL) == 0ULL;
      if (kept && lane < 16) supp |= row;
    }
  }
  if (lane < 16) s_supp[lane] = supp;
  if (lane < n_allowed && lane < 64) s_alw[lane] = allowed[lane];
  __syncthreads();

  // valid flags for entries [lane*16, lane*16+16)
  bool validf[16];
  int cnt = 0;
  #pragma unroll
  for (int k = 0; k < 16; ++k) {
    const int r = lane * 16 + k;
    bool kp = ((s_supp[r >> 6] >> (unsigned)(r & 63)) & 1ULL) == 0ULL;
    float s = t_sc[r];
    int c = t_cl[r];
    bool ina = false;
    for (int q = 0; q < n_allowed; ++q) ina = ina || (c == s_alw[q]);
    bool v = kp && (s > SCORE_THRESH) && ina;
    validf[k] = v;
    cnt += v ? 1 : 0;
  }
  // inclusive scan of cnt across 64 lanes
  int scan = cnt;
  #pragma unroll
  for (int o = 1; o < 64; o <<= 1) {
    int v = __shfl_up(scan, o, 64);
    if (lane >= o) scan += v;
  }
  const int excl = scan - cnt;
  int rk = excl;
  #pragma unroll
  for (int k = 0; k < 16; ++k) {
    if (validf[k]) {
      if (rk < M_MAX) s_selr[rk] = lane * 16 + k;
      rk++;
    }
  }
  if (lane == 63) s_nsel = (scan < M_MAX) ? scan : M_MAX;
  __syncthreads();

  const int nsel = s_nsel;
  if (lane < 32) {
    float b0, b1, b2, b3, fsc, fcl;
    if (lane == 0) {
      b0 = 0.0f; b1 = 0.0f; b2 = (float)(W_IMG - 1); b3 = (float)(H_IMG - 1);
      fsc = 1.0f; fcl = -1.0f;
    } else if (lane <= nsel) {
      int r = s_selr[lane - 1];
      b0 = tb[r]; b1 = tb[PRE_NMS + r]; b2 = tb[2 * PRE_NMS + r]; b3 = tb[3 * PRE_NMS + r];
      fsc = t_sc[r]; fcl = (float)t_cl[r];
    } else {
      b0 = b1 = b2 = b3 = 0.0f; fsc = 0.0f; fcl = 0.0f;
    }
    out[lane * 4 + 0] = b0; out[lane * 4 + 1] = b1;
    out[lane * 4 + 2] = b2; out[lane * 4 + 3] = b3;
    out[128 + lane] = fsc;
    out[160 + lane] = fcl;

    const float ccx = (b0 + b2) * 0.5f;
    const float ccy = (b1 + b3) * 0.5f;
    const float bwd = b2 - b0;
    const float bhd = b3 - b1;
    const float scl3[3] = {0.7071f, 1.0f, 1.4142f};
    #pragma unroll
    for (int s3 = 0; s3 < 3; ++s3) {
      float ww = bwd * scl3[s3] * 0.5f;
      float hh = bhd * scl3[s3] * 0.5f;
      float cx1 = fminf(fmaxf(ccx - ww, 0.0f), (float)(W_IMG - 1));
      float cy1 = fminf(fmaxf(ccy - hh, 0.0f), (float)(H_IMG - 1));
      float cx2 = fminf(fmaxf(ccx + ww, 0.0f), (float)(W_IMG - 1));
      float cy2 = fminf(fmaxf(ccy + hh, 0.0f), (float)(H_IMG - 1));
      const int bi = (lane * 3 + s3) * 4;
      cropbox[bi + 0] = cx1; cropbox[bi + 1] = cy1;
      cropbox[bi + 2] = cx2; cropbox[bi + 3] = cy2;
    }
  }
}

// ---------------------------------------------------------------------------
// K5: 96 crops x 3 channels x 224x224, bilinear + mask + normalize.
// One thread per output pixel; stores fully coalesced.
// ---------------------------------------------------------------------------
__global__ __launch_bounds__(256) void k_crop(
    const float* __restrict__ img, const float* __restrict__ cropbox,
    float* __restrict__ out) {
  const int gid = blockIdx.x * 256 + threadIdx.x;
  const int px = gid % OUT_SZ;
  const int t1 = gid / OUT_SZ;
  const int py = t1 % OUT_SZ;
  const int t2 = t1 / OUT_SZ;
  const int c = t2 % 3;
  const int b = t2 / 3;
  if (b >= 96) return;

  const float bx1 = cropbox[b * 4 + 0];
  const float by1 = cropbox[b * 4 + 1];
  const float bx2 = cropbox[b * 4 + 2];
  const float by2 = cropbox[b * 4 + 3];
  const float bw = (bx2 - bx1) / (float)OUT_SZ;
  const float bh = (by2 - by1) / (float)OUT_SZ;
  const float xs = bx1 - 0.5f + ((float)px + 0.5f) * bw;
  const float ys = by1 - 0.5f + ((float)py + 0.5f) * bh;
  const bool mx = (xs > -1.0f) && (xs < (float)W_IMG);
  const bool my = (ys > -1.0f) && (ys < (float)H_IMG);
  const float xsc = fminf(fmaxf(xs, 0.0f), (float)(W_IMG - 1));
  const float ysc = fminf(fmaxf(ys, 0.0f), (float)(H_IMG - 1));
  const int x0 = (int)floorf(xsc);
  const int y0 = (int)floorf(ysc);
  const int x1i = min(x0 + 1, W_IMG - 1);
  const int y1i = min(y0 + 1, H_IMG - 1);
  const float wx = xsc - (float)x0;
  const float wy = ysc - (float)y0;

  const float* ic = img + (size_t)c * (H_IMG * W_IMG);
  const float p00 = ic[y0 * W_IMG + x0];
  const float p01 = ic[y0 * W_IMG + x1i];
  const float p10 = ic[y1i * W_IMG + x0];
  const float p11 = ic[y1i * W_IMG + x1i];
  const float r0 = p00 * (1.0f - wy) + p10 * wy;
  const float r1 = p01 * (1.0f - wy) + p11 * wy;
  float v = r0 * (1.0f - wx) + r1 * wx;
  v = (mx && my) ? v : 0.0f;

  const float mean = (c == 0) ? 0.485f : ((c == 1) ? 0.456f : 0.406f);
  const float stdv = (c == 0) ? 0.229f : ((c == 1) ? 0.224f : 0.225f);
  out[gid] = (v - mean) / stdv;
}

// ---------------------------------------------------------------------------
extern "C" void kernel_launch(void* const* d_in, const int* in_sizes, int n_in,
                              void* d_out, int out_size, void* d_ws, size_t ws_size,
                              hipStream_t stream) {
  const float* raw = (const float*)d_in[0];
  const float* img = (const float*)d_in[1];
  const int* allowed = (const int*)d_in[2];
  float* out = (float*)d_out;

  unsigned long long* mask = (unsigned long long*)d_ws;
  float* fbase = (float*)((char*)d_ws + (size_t)PRE_NMS * 16 * 8);
  float* x1 = fbase + 0 * N_ANCH;
  float* y1 = fbase + 1 * N_ANCH;
  float* x2 = fbase + 2 * N_ANCH;
  float* y2 = fbase + 3 * N_ANCH;
  float* sc = fbase + 4 * N_ANCH;
  int*   cls = (int*)(fbase + 5 * N_ANCH);
  float* t_sc = fbase + 6 * N_ANCH;
  float* tb   = t_sc + PRE_NMS;
  int*   t_cl = (int*)(tb + 4 * PRE_NMS);
  float* cropbox = (float*)(t_cl + PRE_NMS);

  k_prep<<<(N_ANCH + 63) / 64, 512, 0, stream>>>(raw, x1, y1, x2, y2, sc, cls);
  k_select<<<1, 1024, 0, stream>>>(sc, cls, x1, y1, x2, y2, t_sc, tb, t_cl);
  k_iou_mask<<<64, 256, 0, stream>>>(tb, mask);
  k_nms_final<<<1, 64, 0, stream>>>(mask, t_sc, tb, t_cl, allowed,
                                    in_sizes[2], out, cropbox);
  const int total = 96 * 3 * OUT_SZ * OUT_SZ;
  k_crop<<<(total + 255) / 256, 256, 0, stream>>>(img, cropbox, out + 192);
}

// Round 2
// 157.191 us; speedup vs baseline: 3.2006x; 3.2006x over previous
//
#include <hip/hip_runtime.h>
#include <hip/hip_bf16.h>
#include <stdint.h>

#define N_ANCH   8400
#define NUM_CLS  600
#define H_IMG    640
#define W_IMG    640
#define PRE_NMS  1024
#define M_MAX    31
#define OUT_SZ   224
#define SCORE_THRESH 0.1f
#define IOU_THRESH   0.45f

// ---------------------------------------------------------------------------
// K1: decode boxes + per-anchor max/argmax over 600 classes.
// 512 threads = 64 anchors x 8 class-partitions (75 classes each).
// ---------------------------------------------------------------------------
__global__ __launch_bounds__(512) void k_prep(
    const float* __restrict__ raw,
    float* __restrict__ x1, float* __restrict__ y1,
    float* __restrict__ x2, float* __restrict__ y2,
    float* __restrict__ sc, int* __restrict__ cls) {
  __shared__ float s_m[8][64];
  __shared__ int   s_mi[8][64];
  const int lane = threadIdx.x & 63;
  const int part = threadIdx.x >> 6;       // 0..7
  const int a = blockIdx.x * 64 + lane;

  float m = -INFINITY; int mi = 0;
  if (a < N_ANCH) {
    const float* lp = raw + (size_t)(4 + part * 75) * N_ANCH + a;
    #pragma unroll 5
    for (int cc = 0; cc < 75; ++cc) {
      float v = lp[(size_t)cc * N_ANCH];
      if (v > m) { m = v; mi = part * 75 + cc; }
    }
  }
  s_m[part][lane] = m; s_mi[part][lane] = mi;
  __syncthreads();
  if (part == 0 && a < N_ANCH) {
    #pragma unroll
    for (int p = 1; p < 8; ++p) {
      float vm = s_m[p][lane];
      if (vm > m) { m = vm; mi = s_mi[p][lane]; }   // ascending parts -> ties keep first
    }
    sc[a] = m; cls[a] = mi;
    float cx = raw[a];
    float cy = raw[(size_t)1 * N_ANCH + a];
    float w  = raw[(size_t)2 * N_ANCH + a];
    float h  = raw[(size_t)3 * N_ANCH + a];
    x1[a] = cx - w * 0.5f; y1[a] = cy - h * 0.5f;
    x2[a] = cx + w * 0.5f; y2[a] = cy + h * 0.5f;
  }
}

// ---------------------------------------------------------------------------
// K2: exact top-1024 (score desc, index asc) via 64-bit-key radix select +
// bitonic sort. One block of 1024 threads.
// key = (score_bits << 32) | (0xFFFFFFFF - idx)   (all keys distinct)
// Scores are in [0,1) -> bits 63,62 always 0: start at bit 61.
// Early-exit when bucket count == remaining need (then #{key>=prefix}==1024).
// ---------------------------------------------------------------------------
__global__ __launch_bounds__(1024) void k_select(
    const float* __restrict__ sc, const int* __restrict__ cls,
    const float* __restrict__ x1, const float* __restrict__ y1,
    const float* __restrict__ x2, const float* __restrict__ y2,
    float* __restrict__ t_sc, float* __restrict__ tb, int* __restrict__ t_cl) {
  __shared__ float s_sc[N_ANCH];
  __shared__ unsigned long long s_keys[PRE_NMS];
  __shared__ int s_icnt[16];
  __shared__ int s_tot;
  __shared__ int s_cnt;
  const int tid = threadIdx.x;

  for (int a = tid; a < N_ANCH; a += 1024) s_sc[a] = sc[a];
  if (tid == 0) s_cnt = 0;
  __syncthreads();

  unsigned long long prefix = 0ULL;
  int need = PRE_NMS;
  for (int bit = 61; bit >= 0; --bit) {
    const unsigned long long test   = prefix | (1ULL << bit);
    const unsigned long long maskhi = ~((1ULL << bit) - 1ULL);
    int c = 0;
    for (int a = tid; a < N_ANCH; a += 1024) {
      unsigned long long key =
          (((unsigned long long)__float_as_uint(s_sc[a])) << 32) |
          (unsigned long long)(0xFFFFFFFFu - (unsigned)a);
      if ((key & maskhi) == test) ++c;
    }
    #pragma unroll
    for (int o = 32; o > 0; o >>= 1) c += __shfl_down(c, o, 64);
    if ((tid & 63) == 0) s_icnt[tid >> 6] = c;
    __syncthreads();
    if (tid == 0) {
      int tot = 0;
      #pragma unroll
      for (int wv = 0; wv < 16; ++wv) tot += s_icnt[wv];
      s_tot = tot;
    }
    __syncthreads();
    const int total = s_tot;
    if (total >= need) {
      prefix = test;
      if (total == need) break;     // uniform branch: exactly 1024 keys >= prefix
    } else {
      need -= total;
    }
  }

  // gather the exactly-1024 keys >= prefix (order fixed by the sort below)
  for (int a = tid; a < N_ANCH; a += 1024) {
    unsigned long long key =
        (((unsigned long long)__float_as_uint(s_sc[a])) << 32) |
        (unsigned long long)(0xFFFFFFFFu - (unsigned)a);
    if (key >= prefix) {
      int p = atomicAdd(&s_cnt, 1);
      if (p < PRE_NMS) s_keys[p] = key;
    }
  }
  __syncthreads();

  // bitonic sort, descending
  for (int k = 2; k <= PRE_NMS; k <<= 1) {
    for (int j = k >> 1; j > 0; j >>= 1) {
      __syncthreads();
      const int i = tid;
      const int ixj = i ^ j;
      if (ixj > i) {
        unsigned long long va = s_keys[i], vb = s_keys[ixj];
        bool desc = ((i & k) == 0);
        bool sw = desc ? (va < vb) : (va > vb);
        if (sw) { s_keys[i] = vb; s_keys[ixj] = va; }
      }
    }
  }
  __syncthreads();

  const unsigned long long key = s_keys[tid];
  const int idx = (int)(0xFFFFFFFFu - (unsigned)(key & 0xFFFFFFFFULL));
  t_sc[tid] = __uint_as_float((unsigned)(key >> 32));
  tb[tid]               = x1[idx];
  tb[PRE_NMS + tid]     = y1[idx];
  tb[2 * PRE_NMS + tid] = x2[idx];
  tb[3 * PRE_NMS + tid] = y2[idx];
  t_cl[tid] = cls[idx];
}

// ---------------------------------------------------------------------------
// K3: suppression-mask matrix. mask[i][w] bit b set iff IoU(i, w*64+b)>thr
// and (w*64+b) > i. (Rotated compute order dodges LDS bank conflicts; bit
// placement is standard.)
// ---------------------------------------------------------------------------
__global__ __launch_bounds__(256) void k_iou_mask(
    const float* __restrict__ tb, unsigned long long* __restrict__ mask) {
  __shared__ float bx1[PRE_NMS], by1[PRE_NMS], bx2[PRE_NMS], by2[PRE_NMS], bar[PRE_NMS];
  const int tid = threadIdx.x;
  for (int a = tid; a < PRE_NMS; a += 256) {
    float X1 = tb[a], Y1 = tb[PRE_NMS + a], X2 = tb[2 * PRE_NMS + a], Y2 = tb[3 * PRE_NMS + a];
    bx1[a] = X1; by1[a] = Y1; bx2[a] = X2; by2[a] = Y2;
    bar[a] = (X2 - X1) * (Y2 - Y1);
  }
  __syncthreads();
  const int g = blockIdx.x * 256 + tid;      // 0..16383
  const int i = g >> 4;
  const int w = g & 15;
  const float ix1 = bx1[i], iy1 = by1[i], ix2 = bx2[i], iy2 = by2[i], ia = bar[i];
  unsigned long long m = 0ULL;
  const int j0 = w * 64;
  #pragma unroll 8
  for (int l = 0; l < 64; ++l) {
    const int jj = (l + 4 * w) & 63;
    const int j = j0 + jj;
    float ltx = fmaxf(ix1, bx1[j]);
    float lty = fmaxf(iy1, by1[j]);
    float rbx = fminf(ix2, bx2[j]);
    float rby = fminf(iy2, by2[j]);
    float ww = fmaxf(rbx - ltx, 0.0f);
    float hh = fmaxf(rby - lty, 0.0f);
    float inter = ww * hh;
    float uni = ia + bar[j] - inter;
    float iou = inter / fmaxf(uni, 1e-12f);
    if (iou > IOU_THRESH && j > i) m |= (1ULL << jj);
  }
  mask[(size_t)i * 16 + w] = m;
}

// ---------------------------------------------------------------------------
// K4: greedy-NMS reduce, chunked 64-at-a-time.
//  - 64 lanes load each 64x1024-bit chunk cooperatively (double-buffered).
//  - 64x64 diagonal block gathered to SCALAR regs via readlane; keep/suppress
//    recurrence runs branchless in SALU (no memory / shuffles in the chain).
//  - kept rows' full masks OR'd into per-lane suppression words in parallel.
// Then: valid filter (bitmap class test) + stable first-31 + outputs + crop
// boxes. Single wave.
// ---------------------------------------------------------------------------
__device__ __forceinline__ unsigned long long rdlane64(unsigned long long v, int lane) {
  unsigned int lo = (unsigned int)v;
  unsigned int hi = (unsigned int)(v >> 32);
  unsigned int a = (unsigned int)__builtin_amdgcn_readlane((int)lo, lane);
  unsigned int b = (unsigned int)__builtin_amdgcn_readlane((int)hi, lane);
  return ((unsigned long long)b << 32) | (unsigned long long)a;
}

__global__ __launch_bounds__(64) void k_nms_final(
    const unsigned long long* __restrict__ mask,
    const float* __restrict__ t_sc, const float* __restrict__ tb,
    const int* __restrict__ t_cl, const int* __restrict__ allowed, int n_allowed,
    float* __restrict__ out, float* __restrict__ cropbox) {
  __shared__ unsigned long long s_keep[16];
  __shared__ unsigned long long s_albm[16];   // 600-class bitmap (10 words used)
  __shared__ int s_selr[M_MAX];
  __shared__ int s_nsel;
  const int lane = threadIdx.x;
  const int rg = lane >> 4;      // row group 0..3 (rows rg, rg+4, ..., rg+60)
  const int w  = lane & 15;      // word index 0..15

  if (lane < 16) s_albm[lane] = 0ULL;
  __syncthreads();
  if (lane < n_allowed) {
    int c = allowed[lane];
    atomicOr(&s_albm[c >> 6], 1ULL << (c & 63));
  }

  unsigned long long bufA[16], bufB[16];
  unsigned long long suppw = 0ULL;      // partial suppression word w (rows == rg mod 4)
  unsigned long long pre = 0ULL;        // suppression bits over current chunk's columns

#define LOADC(buf, c)                                                        \
  {                                                                          \
    _Pragma("unroll")                                                        \
    for (int r = 0; r < 16; ++r)                                             \
      buf[r] = mask[(size_t)((c) * 64 + rg + r * 4) * 16 + w];               \
  }

#define PROCC(buf, c)                                                        \
  {                                                                          \
    unsigned long long sup = pre;                                            \
    unsigned long long K = 0ULL;                                             \
    _Pragma("unroll")                                                        \
    for (int i = 0; i < 64; ++i) {                                           \
      unsigned long long d = rdlane64(buf[i >> 2], ((i & 3) << 4) + (c));    \
      unsigned long long nk = ((sup >> i) & 1ULL) ^ 1ULL;                    \
      unsigned long long km = 0ULL - nk;                                     \
      K |= km & (1ULL << i);                                                 \
      sup |= d & km;                                                         \
    }                                                                        \
    if (lane == 0) s_keep[c] = K;                                            \
    _Pragma("unroll")                                                        \
    for (int r = 0; r < 16; ++r) {                                           \
      unsigned long long bit = (K >> (rg + 4 * r)) & 1ULL;                   \
      suppw |= buf[r] & (0ULL - bit);                                        \
    }                                                                        \
    if ((c) + 1 < 16) {                                                      \
      unsigned long long p0 = rdlane64(suppw, (c) + 1);                      \
      unsigned long long p1 = rdlane64(suppw, 16 + (c) + 1);                 \
      unsigned long long p2 = rdlane64(suppw, 32 + (c) + 1);                 \
      unsigned long long p3 = rdlane64(suppw, 48 + (c) + 1);                 \
      pre = (p0 | p1) | (p2 | p3);                                           \
    }                                                                        \
  }

  LOADC(bufA, 0)
  #pragma unroll 1
  for (int c = 0; c < 16; c += 2) {
    if (c + 1 < 16) LOADC(bufB, c + 1)
    PROCC(bufA, c)
    if (c + 2 < 16) LOADC(bufA, c + 2)
    if (c + 1 < 16) PROCC(bufB, c + 1)
  }
#undef LOADC
#undef PROCC

  __syncthreads();

  // valid flags for entries [lane*16, lane*16+16)
  bool validf[16];
  int cnt = 0;
  #pragma unroll
  for (int k = 0; k < 16; ++k) {
    const int r = lane * 16 + k;
    bool kp = ((s_keep[r >> 6] >> (unsigned)(r & 63)) & 1ULL) != 0ULL;
    float s = t_sc[r];
    int c = t_cl[r];
    bool ina = ((s_albm[c >> 6] >> (unsigned)(c & 63)) & 1ULL) != 0ULL;
    bool v = kp && (s > SCORE_THRESH) && ina;
    validf[k] = v;
    cnt += v ? 1 : 0;
  }
  // inclusive scan of cnt across 64 lanes
  int scan = cnt;
  #pragma unroll
  for (int o = 1; o < 64; o <<= 1) {
    int v = __shfl_up(scan, o, 64);
    if (lane >= o) scan += v;
  }
  const int excl = scan - cnt;
  int rk = excl;
  #pragma unroll
  for (int k = 0; k < 16; ++k) {
    if (validf[k]) {
      if (rk < M_MAX) s_selr[rk] = lane * 16 + k;
      rk++;
    }
  }
  if (lane == 63) s_nsel = (scan < M_MAX) ? scan : M_MAX;
  __syncthreads();

  const int nsel = s_nsel;
  if (lane < 32) {
    float b0, b1, b2, b3, fsc, fcl;
    if (lane == 0) {
      b0 = 0.0f; b1 = 0.0f; b2 = (float)(W_IMG - 1); b3 = (float)(H_IMG - 1);
      fsc = 1.0f; fcl = -1.0f;
    } else if (lane <= nsel) {
      int r = s_selr[lane - 1];
      b0 = tb[r]; b1 = tb[PRE_NMS + r]; b2 = tb[2 * PRE_NMS + r]; b3 = tb[3 * PRE_NMS + r];
      fsc = t_sc[r]; fcl = (float)t_cl[r];
    } else {
      b0 = b1 = b2 = b3 = 0.0f; fsc = 0.0f; fcl = 0.0f;
    }
    out[lane * 4 + 0] = b0; out[lane * 4 + 1] = b1;
    out[lane * 4 + 2] = b2; out[lane * 4 + 3] = b3;
    out[128 + lane] = fsc;
    out[160 + lane] = fcl;

    const float ccx = (b0 + b2) * 0.5f;
    const float ccy = (b1 + b3) * 0.5f;
    const float bwd = b2 - b0;
    const float bhd = b3 - b1;
    const float scl3[3] = {0.7071f, 1.0f, 1.4142f};
    #pragma unroll
    for (int s3 = 0; s3 < 3; ++s3) {
      float ww = bwd * scl3[s3] * 0.5f;
      float hh = bhd * scl3[s3] * 0.5f;
      float cx1 = fminf(fmaxf(ccx - ww, 0.0f), (float)(W_IMG - 1));
      float cy1 = fminf(fmaxf(ccy - hh, 0.0f), (float)(H_IMG - 1));
      float cx2 = fminf(fmaxf(ccx + ww, 0.0f), (float)(W_IMG - 1));
      float cy2 = fminf(fmaxf(ccy + hh, 0.0f), (float)(H_IMG - 1));
      const int bi = (lane * 3 + s3) * 4;
      cropbox[bi + 0] = cx1; cropbox[bi + 1] = cy1;
      cropbox[bi + 2] = cx2; cropbox[bi + 3] = cy2;
    }
  }
}

// ---------------------------------------------------------------------------
// K5: 96 crops x 3 channels x 224x224, bilinear + mask + normalize.
// One thread per output pixel; stores fully coalesced.
// ---------------------------------------------------------------------------
__global__ __launch_bounds__(256) void k_crop(
    const float* __restrict__ img, const float* __restrict__ cropbox,
    float* __restrict__ out) {
  const int gid = blockIdx.x * 256 + threadIdx.x;
  const int px = gid % OUT_SZ;
  const int t1 = gid / OUT_SZ;
  const int py = t1 % OUT_SZ;
  const int t2 = t1 / OUT_SZ;
  const int c = t2 % 3;
  const int b = t2 / 3;
  if (b >= 96) return;

  const float bx1 = cropbox[b * 4 + 0];
  const float by1 = cropbox[b * 4 + 1];
  const float bx2 = cropbox[b * 4 + 2];
  const float by2 = cropbox[b * 4 + 3];
  const float bw = (bx2 - bx1) / (float)OUT_SZ;
  const float bh = (by2 - by1) / (float)OUT_SZ;
  const float xs = bx1 - 0.5f + ((float)px + 0.5f) * bw;
  const float ys = by1 - 0.5f + ((float)py + 0.5f) * bh;
  const bool mx = (xs > -1.0f) && (xs < (float)W_IMG);
  const bool my = (ys > -1.0f) && (ys < (float)H_IMG);
  const float xsc = fminf(fmaxf(xs, 0.0f), (float)(W_IMG - 1));
  const float ysc = fminf(fmaxf(ys, 0.0f), (float)(H_IMG - 1));
  const int x0 = (int)floorf(xsc);
  const int y0 = (int)floorf(ysc);
  const int x1i = min(x0 + 1, W_IMG - 1);
  const int y1i = min(y0 + 1, H_IMG - 1);
  const float wx = xsc - (float)x0;
  const float wy = ysc - (float)y0;

  const float* ic = img + (size_t)c * (H_IMG * W_IMG);
  const float p00 = ic[y0 * W_IMG + x0];
  const float p01 = ic[y0 * W_IMG + x1i];
  const float p10 = ic[y1i * W_IMG + x0];
  const float p11 = ic[y1i * W_IMG + x1i];
  const float r0 = p00 * (1.0f - wy) + p10 * wy;
  const float r1 = p01 * (1.0f - wy) + p11 * wy;
  float v = r0 * (1.0f - wx) + r1 * wx;
  v = (mx && my) ? v : 0.0f;

  const float mean = (c == 0) ? 0.485f : ((c == 1) ? 0.456f : 0.406f);
  const float stdv = (c == 0) ? 0.229f : ((c == 1) ? 0.224f : 0.225f);
  out[gid] = (v - mean) / stdv;
}

// ---------------------------------------------------------------------------
extern "C" void kernel_launch(void* const* d_in, const int* in_sizes, int n_in,
                              void* d_out, int out_size, void* d_ws, size_t ws_size,
                              hipStream_t stream) {
  const float* raw = (const float*)d_in[0];
  const float* img = (const float*)d_in[1];
  const int* allowed = (const int*)d_in[2];
  float* out = (float*)d_out;

  unsigned long long* mask = (unsigned long long*)d_ws;
  float* fbase = (float*)((char*)d_ws + (size_t)PRE_NMS * 16 * 8);
  float* x1 = fbase + 0 * N_ANCH;
  float* y1 = fbase + 1 * N_ANCH;
  float* x2 = fbase + 2 * N_ANCH;
  float* y2 = fbase + 3 * N_ANCH;
  float* sc = fbase + 4 * N_ANCH;
  int*   cls = (int*)(fbase + 5 * N_ANCH);
  float* t_sc = fbase + 6 * N_ANCH;
  float* tb   = t_sc + PRE_NMS;
  int*   t_cl = (int*)(tb + 4 * PRE_NMS);
  float* cropbox = (float*)(t_cl + PRE_NMS);

  k_prep<<<(N_ANCH + 63) / 64, 512, 0, stream>>>(raw, x1, y1, x2, y2, sc, cls);
  k_select<<<1, 1024, 0, stream>>>(sc, cls, x1, y1, x2, y2, t_sc, tb, t_cl);
  k_iou_mask<<<64, 256, 0, stream>>>(tb, mask);
  k_nms_final<<<1, 64, 0, stream>>>(mask, t_sc, tb, t_cl, allowed,
                                    in_sizes[2], out, cropbox);
  const int total = 96 * 3 * OUT_SZ * OUT_SZ;
  k_crop<<<(total + 255) / 256, 256, 0, stream>>>(img, cropbox, out + 192);
}